// Round 1
// baseline (336.401 us; speedup 1.0000x reference)
//
#include <hip/hip_runtime.h>
#include <hip/hip_bf16.h>
#include <stdint.h>

#define IN_F 4096
#define OUT_F 11008
#define TOKENS 32
#define NELEM_W (OUT_F * IN_F)   // 45088768 weights, ~180 MB fp32

typedef __attribute__((ext_vector_type(8))) __bf16 bf16x8;
typedef __attribute__((ext_vector_type(4))) float  f32x4;

// ---------------- pass 1: sum(|w|) over all weights ----------------
__global__ __launch_bounds__(256) void absum_kernel(const float* __restrict__ w,
                                                    double* __restrict__ ws_sum) {
    int tid = blockIdx.x * blockDim.x + threadIdx.x;
    int stride = gridDim.x * blockDim.x;
    const float4* w4 = (const float4*)w;
    const int n4 = NELEM_W / 4;
    float s = 0.f;
    for (int i = tid; i < n4; i += stride) {
        float4 v = w4[i];
        s += fabsf(v.x) + fabsf(v.y) + fabsf(v.z) + fabsf(v.w);
    }
    // wave (64-lane) shuffle reduction
    for (int off = 32; off > 0; off >>= 1)
        s += __shfl_down(s, off, 64);
    __shared__ float wsum[4];   // 256 threads = 4 waves
    int lane = threadIdx.x & 63;
    int wv   = threadIdx.x >> 6;
    if (lane == 0) wsum[wv] = s;
    __syncthreads();
    if (threadIdx.x == 0) {
        float t = wsum[0] + wsum[1] + wsum[2] + wsum[3];
        atomicAdd(ws_sum, (double)t);   // f64 global atomic, hw-supported
    }
}

// ---------------- pass 1.5: abs_mean / threshold ----------------
__global__ void finalize_kernel(double* __restrict__ ws) {
    double mean = ws[0] / (double)NELEM_W;
    if (mean < 1e-5) mean = 1e-5;
    float mf = (float)mean;
    float* f = (float*)ws;
    f[2] = 0.7f * mf;   // threshold
    f[3] = mf;          // output scale (abs_mean)
}

// ---------------- pass 2 helpers ----------------
// ternarize one fp32 weight -> fp32 bit pattern of {0, +1.0, -1.0}
__device__ __forceinline__ uint32_t tern1(float v, float thr) {
    uint32_t u  = __float_as_uint(v);
    uint32_t pm = (u & 0x80000000u) | 0x3F800000u;   // +-1.0f
    return (__builtin_fabsf(v) > thr) ? pm : 0u;
}

// 8 fp32 weights -> bf16x8 fragment of {0,+-1}
__device__ __forceinline__ bf16x8 tern8(float4 b0, float4 b1, float thr) {
    uint32_t q0 = tern1(b0.x, thr), q1 = tern1(b0.y, thr);
    uint32_t q2 = tern1(b0.z, thr), q3 = tern1(b0.w, thr);
    uint32_t q4 = tern1(b1.x, thr), q5 = tern1(b1.y, thr);
    uint32_t q6 = tern1(b1.z, thr), q7 = tern1(b1.w, thr);
    union { uint32_t u[4]; bf16x8 v; } U;
    // bf16 of +-1.0f / 0.0f is the top 16 bits (low 16 are zero)
    U.u[0] = (q0 >> 16) | (q1 & 0xFFFF0000u);
    U.u[1] = (q2 >> 16) | (q3 & 0xFFFF0000u);
    U.u[2] = (q4 >> 16) | (q5 & 0xFFFF0000u);
    U.u[3] = (q6 >> 16) | (q7 & 0xFFFF0000u);
    return U.v;
}

// fp32 -> bf16 bits (round-to-nearest-even), result in low 16
__device__ __forceinline__ uint32_t bfr(float v) {
    uint32_t u = __float_as_uint(v);
    uint32_t r = u + 0x7FFFu + ((u >> 16) & 1u);
    return r >> 16;
}

// 8 fp32 x-values -> bf16x8 fragment
__device__ __forceinline__ bf16x8 cvt8(float4 a0, float4 a1) {
    union { uint32_t u[4]; bf16x8 v; } U;
    U.u[0] = bfr(a0.x) | (bfr(a0.y) << 16);
    U.u[1] = bfr(a0.z) | (bfr(a0.w) << 16);
    U.u[2] = bfr(a1.x) | (bfr(a1.y) << 16);
    U.u[3] = bfr(a1.z) | (bfr(a1.w) << 16);
    return U.v;
}

// ---------------- pass 2: skinny ternary GEMM via MFMA ----------------
// grid: 688 o-groups (16 cols each) x 8 K-chunks (512 each); 1 wave per block.
// out[t][o] partials combined with atomicAdd into zeroed d_out.
#define KSPLIT 8
#define KCHUNK (IN_F / KSPLIT)      // 512
#define KSTEPS (KCHUNK / 32)        // 16

__global__ __launch_bounds__(64, 4) void ternary_gemm(const float* __restrict__ x,
                                                      const float* __restrict__ w,
                                                      const float* __restrict__ wsf,
                                                      float* __restrict__ out) {
    const float thr   = wsf[2];
    const float scale = wsf[3];
    const int bid  = blockIdx.x;
    const int og   = bid >> 3;          // 0..687
    const int kc   = bid & (KSPLIT - 1);
    const int lane = threadIdx.x;       // 0..63
    const int col  = lane & 15;         // o within group / A row (t)
    const int quad = lane >> 4;         // k sub-block

    const float* wp  = w + (size_t)(og * 16 + col) * IN_F + kc * KCHUNK + quad * 8;
    const float* xp0 = x + (size_t)col * IN_F + kc * KCHUNK + quad * 8;   // t = col
    const float* xp1 = xp0 + (size_t)16 * IN_F;                           // t = col+16

    f32x4 acc0 = {0.f, 0.f, 0.f, 0.f};
    f32x4 acc1 = {0.f, 0.f, 0.f, 0.f};

#pragma unroll 4
    for (int s = 0; s < KSTEPS; ++s) {
        float4 b0 = *(const float4*)(wp);
        float4 b1 = *(const float4*)(wp + 4);
        float4 a0 = *(const float4*)(xp0);
        float4 a1 = *(const float4*)(xp0 + 4);
        float4 a2 = *(const float4*)(xp1);
        float4 a3 = *(const float4*)(xp1 + 4);
        wp  += 32;
        xp0 += 32;
        xp1 += 32;

        bf16x8 bf  = tern8(b0, b1, thr);
        bf16x8 af0 = cvt8(a0, a1);
        bf16x8 af1 = cvt8(a2, a3);

        acc0 = __builtin_amdgcn_mfma_f32_16x16x32_bf16(af0, bf, acc0, 0, 0, 0);
        acc1 = __builtin_amdgcn_mfma_f32_16x16x32_bf16(af1, bf, acc1, 0, 0, 0);
    }

    // epilogue: D layout col=lane&15, row=quad*4+reg
    const int obase = og * 16 + col;
#pragma unroll
    for (int r = 0; r < 4; ++r) {
        int t0 = quad * 4 + r;
        atomicAdd(out + (size_t)t0 * OUT_F + obase,        scale * acc0[r]);
        atomicAdd(out + (size_t)(t0 + 16) * OUT_F + obase, scale * acc1[r]);
    }
}

extern "C" void kernel_launch(void* const* d_in, const int* in_sizes, int n_in,
                              void* d_out, int out_size, void* d_ws, size_t ws_size,
                              hipStream_t stream) {
    const float* x = (const float*)d_in[0];   // [32, 4096]
    const float* w = (const float*)d_in[1];   // [11008, 4096]
    float* out     = (float*)d_out;           // [32, 11008]
    double* wsd    = (double*)d_ws;

    hipMemsetAsync(d_ws, 0, 16, stream);                               // zero sum accumulator
    hipMemsetAsync(d_out, 0, sizeof(float) * TOKENS * OUT_F, stream);  // zero for atomics

    absum_kernel<<<2048, 256, 0, stream>>>(w, wsd);
    finalize_kernel<<<1, 1, 0, stream>>>(wsd);
    ternary_gemm<<<(OUT_F / 16) * KSPLIT, 64, 0, stream>>>(x, w, (const float*)d_ws, out);
}

// Round 2
// 305.932 us; speedup vs baseline: 1.0996x; 1.0996x over previous
//
#include <hip/hip_runtime.h>
#include <hip/hip_bf16.h>
#include <stdint.h>

#define IN_F 4096
#define OUT_F 11008
#define TOKENS 32
#define NELEM_W (OUT_F * IN_F)   // 45088768 weights, ~180 MB fp32

typedef __attribute__((ext_vector_type(8))) __bf16 bf16x8;
typedef __attribute__((ext_vector_type(4))) float  f32x4;

// fp32 -> bf16 bits (round-to-nearest-even), result in low 16
__device__ __forceinline__ uint32_t bfr(float v) {
    uint32_t u = __float_as_uint(v);
    uint32_t r = u + 0x7FFFu + ((u >> 16) & 1u);
    return r >> 16;
}

// ---------------- pass 1: sum(|w|) + x->bf16 conversion ----------------
// blocks [0, 2048): grid-stride abs-sum of w
// blocks [2048, 2048+64): convert x (131072 floats) to bf16 into xb
#define ABSUM_BLOCKS 2048
#define XCVT_BLOCKS  64

__global__ __launch_bounds__(256) void absum_xcvt_kernel(const float* __restrict__ w,
                                                         const float* __restrict__ x,
                                                         double* __restrict__ ws_sum,
                                                         uint4* __restrict__ xb) {
    if (blockIdx.x >= ABSUM_BLOCKS) {
        // x conversion: 16384 threads, 8 floats each
        int i = (blockIdx.x - ABSUM_BLOCKS) * 256 + threadIdx.x;
        const float4* x4 = (const float4*)x;
        float4 a0 = x4[i * 2];
        float4 a1 = x4[i * 2 + 1];
        uint4 o;
        o.x = bfr(a0.x) | (bfr(a0.y) << 16);
        o.y = bfr(a0.z) | (bfr(a0.w) << 16);
        o.z = bfr(a1.x) | (bfr(a1.y) << 16);
        o.w = bfr(a1.z) | (bfr(a1.w) << 16);
        xb[i] = o;
        return;
    }
    int tid = blockIdx.x * blockDim.x + threadIdx.x;
    int stride = ABSUM_BLOCKS * 256;
    const float4* w4 = (const float4*)w;
    const int n4 = NELEM_W / 4;
    float s = 0.f;
    for (int i = tid; i < n4; i += stride) {
        float4 v = w4[i];
        s += fabsf(v.x) + fabsf(v.y) + fabsf(v.z) + fabsf(v.w);
    }
    for (int off = 32; off > 0; off >>= 1)
        s += __shfl_down(s, off, 64);
    __shared__ float wsum[4];
    int lane = threadIdx.x & 63;
    int wv   = threadIdx.x >> 6;
    if (lane == 0) wsum[wv] = s;
    __syncthreads();
    if (threadIdx.x == 0) {
        float t = wsum[0] + wsum[1] + wsum[2] + wsum[3];
        atomicAdd(ws_sum, (double)t);
    }
}

// ---------------- pass 1.5: abs_mean / threshold ----------------
__global__ void finalize_kernel(double* __restrict__ ws) {
    double mean = ws[0] / (double)NELEM_W;
    if (mean < 1e-5) mean = 1e-5;
    float mf = (float)mean;
    float* f = (float*)ws;
    f[2] = 0.7f * mf;   // threshold
    f[3] = mf;          // scale
}

// ---------------- pass 2 helpers ----------------
__device__ __forceinline__ uint32_t tern1(float v, float thr) {
    uint32_t u  = __float_as_uint(v);
    uint32_t pm = (u & 0x80000000u) | 0x3F800000u;   // +-1.0f
    return (__builtin_fabsf(v) > thr) ? pm : 0u;
}

__device__ __forceinline__ bf16x8 tern8(float4 b0, float4 b1, float thr) {
    uint32_t q0 = tern1(b0.x, thr), q1 = tern1(b0.y, thr);
    uint32_t q2 = tern1(b0.z, thr), q3 = tern1(b0.w, thr);
    uint32_t q4 = tern1(b1.x, thr), q5 = tern1(b1.y, thr);
    uint32_t q6 = tern1(b1.z, thr), q7 = tern1(b1.w, thr);
    union { uint32_t u[4]; bf16x8 v; } U;
    U.u[0] = (q0 >> 16) | (q1 & 0xFFFF0000u);
    U.u[1] = (q2 >> 16) | (q3 & 0xFFFF0000u);
    U.u[2] = (q4 >> 16) | (q5 & 0xFFFF0000u);
    U.u[3] = (q6 >> 16) | (q7 & 0xFFFF0000u);
    return U.v;
}

// ---------------- pass 2: skinny ternary GEMM via MFMA ----------------
// block = 256 threads (4 waves). Block og owns output cols [og*16, og*16+16).
// Wave wv handles K range [wv*1024, (wv+1)*1024). LDS-combine, store once.
#define KSTEPS 32   // 32 steps x 32 k = 1024 per wave

__global__ __launch_bounds__(256) void ternary_gemm(const float* __restrict__ w,
                                                    const float* __restrict__ wsf,
                                                    const __bf16* __restrict__ xb,
                                                    float* __restrict__ out) {
    __shared__ float red[4 * 512];   // [wave][a(2)][r(4)][lane(64)]
    const float thr   = wsf[2];
    const float scale = wsf[3];
    const int og   = blockIdx.x;
    const int tid  = threadIdx.x;
    const int wv   = tid >> 6;
    const int lane = tid & 63;
    const int col  = lane & 15;     // output col within group; also token for A
    const int quad = lane >> 4;

    const int kbase = wv * 1024 + quad * 8;
    const float*  wp  = w  + (size_t)(og * 16 + col) * IN_F + kbase;
    const __bf16* xp0 = xb + (size_t)col * IN_F + kbase;          // token = col
    const __bf16* xp1 = xp0 + (size_t)16 * IN_F;                  // token = col+16

    f32x4 acc0 = {0.f, 0.f, 0.f, 0.f};
    f32x4 acc1 = {0.f, 0.f, 0.f, 0.f};

#pragma unroll 4
    for (int s = 0; s < KSTEPS; ++s) {
        float4 b0 = *(const float4*)(wp);
        float4 b1 = *(const float4*)(wp + 4);
        bf16x8 a0 = *(const bf16x8*)(xp0);
        bf16x8 a1 = *(const bf16x8*)(xp1);
        wp  += 32;
        xp0 += 32;
        xp1 += 32;

        bf16x8 bf = tern8(b0, b1, thr);
        acc0 = __builtin_amdgcn_mfma_f32_16x16x32_bf16(a0, bf, acc0, 0, 0, 0);
        acc1 = __builtin_amdgcn_mfma_f32_16x16x32_bf16(a1, bf, acc1, 0, 0, 0);
    }

    // stash partials: acc0 token = quad*4+r, acc1 token = 16+quad*4+r, col
    {
        float* base = red + wv * 512;
#pragma unroll
        for (int r = 0; r < 4; ++r) base[r * 64 + lane]       = acc0[r];
#pragma unroll
        for (int r = 0; r < 4; ++r) base[256 + r * 64 + lane] = acc1[r];
    }
    __syncthreads();

    // 512 outputs (32 tokens x 16 cols), 2 per thread, summed over 4 waves
#pragma unroll
    for (int p = tid; p < 512; p += 256) {
        int t = p >> 4, c = p & 15;
        int a = t >> 4;
        int q = (t >> 2) & 3;
        int r = t & 3;
        int idx = a * 256 + r * 64 + q * 16 + c;
        float s = red[idx] + red[512 + idx] + red[1024 + idx] + red[1536 + idx];
        out[(size_t)t * OUT_F + og * 16 + c] = s * scale;
    }
}

extern "C" void kernel_launch(void* const* d_in, const int* in_sizes, int n_in,
                              void* d_out, int out_size, void* d_ws, size_t ws_size,
                              hipStream_t stream) {
    const float* x = (const float*)d_in[0];   // [32, 4096]
    const float* w = (const float*)d_in[1];   // [11008, 4096]
    float* out     = (float*)d_out;           // [32, 11008]
    double* wsd    = (double*)d_ws;
    uint4* xb      = (uint4*)((char*)d_ws + 64);   // 256 KB bf16 x

    hipMemsetAsync(d_ws, 0, 16, stream);   // zero the f64 sum accumulator

    absum_xcvt_kernel<<<ABSUM_BLOCKS + XCVT_BLOCKS, 256, 0, stream>>>(w, x, wsd, xb);
    finalize_kernel<<<1, 1, 0, stream>>>(wsd);
    ternary_gemm<<<OUT_F / 16, 256, 0, stream>>>(w, (const float*)d_ws,
                                                 (const __bf16*)((char*)d_ws + 64), out);
}

// Round 3
// 300.825 us; speedup vs baseline: 1.1183x; 1.0170x over previous
//
#include <hip/hip_runtime.h>
#include <hip/hip_bf16.h>
#include <stdint.h>

#define IN_F 4096
#define OUT_F 11008
#define TOKENS 32
#define NELEM_W (OUT_F * IN_F)   // 45088768 weights, ~180 MB fp32

typedef __attribute__((ext_vector_type(8))) __bf16 bf16x8;
typedef __attribute__((ext_vector_type(4))) float  f32x4;

// fp32 -> bf16 bits (round-to-nearest-even), result in low 16
__device__ __forceinline__ uint32_t bfr(float v) {
    uint32_t u = __float_as_uint(v);
    uint32_t r = u + 0x7FFFu + ((u >> 16) & 1u);
    return r >> 16;
}

// ---------------- pass 1: sum(|w|) + x->bf16 conversion ----------------
#define ABSUM_BLOCKS 2048
#define XCVT_BLOCKS  64

__global__ __launch_bounds__(256) void absum_xcvt_kernel(const float* __restrict__ w,
                                                         const float* __restrict__ x,
                                                         double* __restrict__ ws_sum,
                                                         uint4* __restrict__ xb) {
    if (blockIdx.x >= ABSUM_BLOCKS) {
        // x conversion: 16384 threads, 8 floats each
        int i = (blockIdx.x - ABSUM_BLOCKS) * 256 + threadIdx.x;
        const float4* x4 = (const float4*)x;
        float4 a0 = x4[i * 2];
        float4 a1 = x4[i * 2 + 1];
        uint4 o;
        o.x = bfr(a0.x) | (bfr(a0.y) << 16);
        o.y = bfr(a0.z) | (bfr(a0.w) << 16);
        o.z = bfr(a1.x) | (bfr(a1.y) << 16);
        o.w = bfr(a1.z) | (bfr(a1.w) << 16);
        xb[i] = o;
        return;
    }
    int tid = blockIdx.x * blockDim.x + threadIdx.x;
    int stride = ABSUM_BLOCKS * 256;
    const float4* w4 = (const float4*)w;
    const int n4 = NELEM_W / 4;
    float s = 0.f;
    for (int i = tid; i < n4; i += stride) {
        float4 v = w4[i];
        s += fabsf(v.x) + fabsf(v.y) + fabsf(v.z) + fabsf(v.w);
    }
    for (int off = 32; off > 0; off >>= 1)
        s += __shfl_down(s, off, 64);
    __shared__ float wsum[4];
    int lane = threadIdx.x & 63;
    int wv   = threadIdx.x >> 6;
    if (lane == 0) wsum[wv] = s;
    __syncthreads();
    if (threadIdx.x == 0) {
        float t = wsum[0] + wsum[1] + wsum[2] + wsum[3];
        atomicAdd(ws_sum, (double)t);
    }
}

// ---------------- pass 1.5: abs_mean / threshold ----------------
__global__ void finalize_kernel(double* __restrict__ ws) {
    double mean = ws[0] / (double)NELEM_W;
    if (mean < 1e-5) mean = 1e-5;
    float mf = (float)mean;
    float* f = (float*)ws;
    f[2] = 0.7f * mf;   // threshold
    f[3] = mf;          // scale
}

// ---------------- ternarize helpers ----------------
__device__ __forceinline__ uint32_t tern1(float v, float thr) {
    uint32_t u  = __float_as_uint(v);
    uint32_t pm = (u & 0x80000000u) | 0x3F800000u;   // +-1.0f
    return (__builtin_fabsf(v) > thr) ? pm : 0u;
}

__device__ __forceinline__ bf16x8 tern8(float4 b0, float4 b1, float thr) {
    uint32_t q0 = tern1(b0.x, thr), q1 = tern1(b0.y, thr);
    uint32_t q2 = tern1(b0.z, thr), q3 = tern1(b0.w, thr);
    uint32_t q4 = tern1(b1.x, thr), q5 = tern1(b1.y, thr);
    uint32_t q6 = tern1(b1.z, thr), q7 = tern1(b1.w, thr);
    union { uint32_t u[4]; bf16x8 v; } U;
    U.u[0] = (q0 >> 16) | (q1 & 0xFFFF0000u);
    U.u[1] = (q2 >> 16) | (q3 & 0xFFFF0000u);
    U.u[2] = (q4 >> 16) | (q5 & 0xFFFF0000u);
    U.u[3] = (q6 >> 16) | (q7 & 0xFFFF0000u);
    return U.v;
}

// ---------------- pass 2: LDS-staged ternary GEMM ----------------
// Grid: 688 o-groups x 2 K-halves = 1376 blocks of 256 (4 waves) ~= 5.4/CU.
// Wave wv covers K range [kh*2048 + wv*512, +512) in 8 chunks of 64.
// Staging: lane l loads 16 consecutive floats of row l>>2 (coalesced: each
// 64-lane instr touches 16 fully-used lines), ternarizes to bf16, writes LDS.
// LDS row stride 144 B (pad 16) -> fragment ds_read_b128 is 2-way/free banks.
// Epilogue: 4-wave LDS reduce, one atomicAdd per output (2-way contention).
#define CHUNKS 8
#define WAVE_LDS 2304          // 16 rows * 144 B
#define SMEM_BYTES 9216        // max(4*2304, 4*512*4)

__global__ __launch_bounds__(256, 4) void ternary_gemm(const float* __restrict__ w,
                                                       const float* __restrict__ wsf,
                                                       const __bf16* __restrict__ xb,
                                                       float* __restrict__ out) {
    __shared__ char smem_raw[SMEM_BYTES];
    const float thr   = wsf[2];
    const float scale = wsf[3];
    const int og   = blockIdx.x >> 1;
    const int kh   = blockIdx.x & 1;
    const int tid  = threadIdx.x;
    const int wv   = tid >> 6;
    const int lane = tid & 63;
    const int col  = lane & 15;     // fragment: output col in group / token
    const int quad = lane >> 4;     // fragment: k sub-block
    const int srow = lane >> 2;     // staging: row 0..15
    const int scol = lane & 3;      // staging: 16-float slot within 64k chunk

    const int kbase = kh * 2048 + wv * 512;

    const float* wp = w + (size_t)(og * 16 + srow) * IN_F + kbase + scol * 16;
    char* stage = smem_raw + wv * WAVE_LDS;
    char* wr0   = stage + srow * 144 + scol * 32;
    const char* rd = stage + col * 144;
    const __bf16* xp = xb + (size_t)col * IN_F + kbase + quad * 8;

    f32x4 acc0 = {0.f, 0.f, 0.f, 0.f};
    f32x4 acc1 = {0.f, 0.f, 0.f, 0.f};

    // prefetch chunk 0 (16 floats = 4 x float4, 64 B contiguous per lane)
    float4 f0 = ((const float4*)wp)[0];
    float4 f1 = ((const float4*)wp)[1];
    float4 f2 = ((const float4*)wp)[2];
    float4 f3 = ((const float4*)wp)[3];

    for (int c = 0; c < CHUNKS; ++c) {
        bf16x8 t0 = tern8(f0, f1, thr);
        bf16x8 t1 = tern8(f2, f3, thr);
        *(bf16x8*)(wr0)      = t0;   // granules 2*scol, 2*scol+1
        *(bf16x8*)(wr0 + 16) = t1;

        if (c + 1 < CHUNKS) {        // prefetch next chunk while LDS settles
            const float4* np = (const float4*)(wp + (c + 1) * 64);
            f0 = np[0]; f1 = np[1]; f2 = np[2]; f3 = np[3];
        }

#pragma unroll
        for (int s = 0; s < 2; ++s) {
            // w fragment: granule s*4+quad of row col (intra-wave DS ordering)
            bf16x8 bw = *(const bf16x8*)(rd + (s * 4 + quad) * 16);
            bf16x8 a0 = *(const bf16x8*)(xp + c * 64 + s * 32);
            bf16x8 a1 = *(const bf16x8*)(xp + c * 64 + s * 32 + 16 * IN_F);
            acc0 = __builtin_amdgcn_mfma_f32_16x16x32_bf16(a0, bw, acc0, 0, 0, 0);
            acc1 = __builtin_amdgcn_mfma_f32_16x16x32_bf16(a1, bw, acc1, 0, 0, 0);
        }
    }

    __syncthreads();
    float* red  = (float*)smem_raw;
    float* base = red + wv * 512;
#pragma unroll
    for (int r = 0; r < 4; ++r) base[r * 64 + lane]       = acc0[r];
#pragma unroll
    for (int r = 0; r < 4; ++r) base[256 + r * 64 + lane] = acc1[r];
    __syncthreads();

    // 512 outputs (32 tokens x 16 cols), 2 per thread, summed over 4 waves
#pragma unroll
    for (int p = tid; p < 512; p += 256) {
        int t = p >> 4, cc = p & 15;
        int a = t >> 4;
        int q = (t >> 2) & 3;
        int r = t & 3;
        int idx = a * 256 + r * 64 + q * 16 + cc;
        float s = red[idx] + red[512 + idx] + red[1024 + idx] + red[1536 + idx];
        atomicAdd(out + (size_t)t * OUT_F + og * 16 + cc, s * scale);
    }
}

extern "C" void kernel_launch(void* const* d_in, const int* in_sizes, int n_in,
                              void* d_out, int out_size, void* d_ws, size_t ws_size,
                              hipStream_t stream) {
    const float* x = (const float*)d_in[0];   // [32, 4096]
    const float* w = (const float*)d_in[1];   // [11008, 4096]
    float* out     = (float*)d_out;           // [32, 11008]
    double* wsd    = (double*)d_ws;
    uint4* xb      = (uint4*)((char*)d_ws + 64);   // 256 KB bf16 x

    hipMemsetAsync(d_ws, 0, 16, stream);                               // f64 accumulator
    hipMemsetAsync(d_out, 0, sizeof(float) * TOKENS * OUT_F, stream);  // zero for atomics

    absum_xcvt_kernel<<<ABSUM_BLOCKS + XCVT_BLOCKS, 256, 0, stream>>>(w, x, wsd, xb);
    finalize_kernel<<<1, 1, 0, stream>>>(wsd);
    ternary_gemm<<<(OUT_F / 16) * 2, 256, 0, stream>>>(w, (const float*)d_ws,
                                                       (const __bf16*)((char*)d_ws + 64), out);
}

// Round 4
// 293.009 us; speedup vs baseline: 1.1481x; 1.0267x over previous
//
#include <hip/hip_runtime.h>
#include <hip/hip_bf16.h>
#include <stdint.h>

#define IN_F 4096
#define OUT_F 11008
#define TOKENS 32
#define NELEM_W (OUT_F * IN_F)   // 45088768 weights, ~180 MB fp32

typedef __attribute__((ext_vector_type(8))) __bf16 bf16x8;
typedef __attribute__((ext_vector_type(4))) float  f32x4;

// fp32 -> bf16 bits (round-to-nearest-even), result in low 16
__device__ __forceinline__ uint32_t bfr(float v) {
    uint32_t u = __float_as_uint(v);
    uint32_t r = u + 0x7FFFu + ((u >> 16) & 1u);
    return r >> 16;
}

// ---------------- pass 1: sum(|w|) + x->bf16 conversion ----------------
#define ABSUM_BLOCKS 2048
#define XCVT_BLOCKS  64

__global__ __launch_bounds__(256) void absum_xcvt_kernel(const float* __restrict__ w,
                                                         const float* __restrict__ x,
                                                         double* __restrict__ ws_sum,
                                                         uint4* __restrict__ xb) {
    if (blockIdx.x >= ABSUM_BLOCKS) {
        // x conversion: 16384 threads, 8 floats each
        int i = (blockIdx.x - ABSUM_BLOCKS) * 256 + threadIdx.x;
        const float4* x4 = (const float4*)x;
        float4 a0 = x4[i * 2];
        float4 a1 = x4[i * 2 + 1];
        uint4 o;
        o.x = bfr(a0.x) | (bfr(a0.y) << 16);
        o.y = bfr(a0.z) | (bfr(a0.w) << 16);
        o.z = bfr(a1.x) | (bfr(a1.y) << 16);
        o.w = bfr(a1.z) | (bfr(a1.w) << 16);
        xb[i] = o;
        return;
    }
    int tid = blockIdx.x * blockDim.x + threadIdx.x;
    int stride = ABSUM_BLOCKS * 256;
    const float4* w4 = (const float4*)w;
    const int n4 = NELEM_W / 4;
    float s = 0.f;
    for (int i = tid; i < n4; i += stride) {
        float4 v = w4[i];
        s += fabsf(v.x) + fabsf(v.y) + fabsf(v.z) + fabsf(v.w);
    }
    for (int off = 32; off > 0; off >>= 1)
        s += __shfl_down(s, off, 64);
    __shared__ float wsum[4];
    int lane = threadIdx.x & 63;
    int wv   = threadIdx.x >> 6;
    if (lane == 0) wsum[wv] = s;
    __syncthreads();
    if (threadIdx.x == 0) {
        float t = wsum[0] + wsum[1] + wsum[2] + wsum[3];
        atomicAdd(ws_sum, (double)t);
    }
}

// ---------------- pass 1.5: abs_mean / threshold ----------------
__global__ void finalize_kernel(double* __restrict__ ws) {
    double mean = ws[0] / (double)NELEM_W;
    if (mean < 1e-5) mean = 1e-5;
    float mf = (float)mean;
    float* f = (float*)ws;
    f[2] = 0.7f * mf;   // threshold
    f[3] = mf;          // scale
}

// ---------------- ternarize helpers ----------------
__device__ __forceinline__ uint32_t tern1(float v, float thr) {
    uint32_t u  = __float_as_uint(v);
    uint32_t pm = (u & 0x80000000u) | 0x3F800000u;   // +-1.0f
    return (__builtin_fabsf(v) > thr) ? pm : 0u;
}

// 4 fp32 -> 4 bf16 ternary values packed in uint2
__device__ __forceinline__ uint2 tern4(float4 b, float thr) {
    uint32_t q0 = tern1(b.x, thr), q1 = tern1(b.y, thr);
    uint32_t q2 = tern1(b.z, thr), q3 = tern1(b.w, thr);
    uint2 r;
    r.x = (q0 >> 16) | (q1 & 0xFFFF0000u);
    r.y = (q2 >> 16) | (q3 & 0xFFFF0000u);
    return r;
}

// ---------------- pass 2: LDS-staged ternary GEMM ----------------
// Grid: 688 o-groups x 2 K-halves = 1376 blocks of 256 (4 waves).
// Wave wv covers K range [kh*2048 + wv*512, +512) in 8 chunks of 64.
// W staging, chunk c, instr j (j=0..3): lane l loads 16 B at
//   row og*16 + 4j + (l>>4), float offset (l&15)*4  -> 16 lanes x 16 B
//   contiguous per row = 16 fully-used 64B lines per instruction.
// Ternarize in regs -> LDS bf16, row stride 144 B (b128 frag reads 2-way=free).
// 1-deep register double-buffer of both w and x; #pragma unroll 2 only
// (NO full unroll -> bounded VGPRs, no spills). launch_bounds(256,3).
#define CHUNKS 8
#define WAVE_LDS 2304          // 16 rows * 144 B
#define SMEM_BYTES 9216        // max(4*2304, 4*512*4)

__global__ __launch_bounds__(256, 3) void ternary_gemm(const float* __restrict__ w,
                                                       const float* __restrict__ wsf,
                                                       const __bf16* __restrict__ xb,
                                                       float* __restrict__ out) {
    __shared__ char smem_raw[SMEM_BYTES];
    const float thr   = wsf[2];
    const float scale = wsf[3];
    const int og   = blockIdx.x >> 1;
    const int kh   = blockIdx.x & 1;
    const int tid  = threadIdx.x;
    const int wv   = tid >> 6;
    const int lane = tid & 63;
    const int col  = lane & 15;     // fragment: output col in group / token
    const int quad = lane >> 4;     // fragment: k sub-block; also staging row grp
    const int rlan = lane & 15;     // staging: 16-B slot within a row

    const int kw = kh * 2048 + wv * 512;

    const float* wp = w + (size_t)(og * 16 + quad) * IN_F + kw + rlan * 4;
    char* stage = smem_raw + wv * WAVE_LDS;
    char* wr    = stage + quad * 144 + rlan * 8;   // + j*576 per instr
    const char* rd = stage + col * 144;
    const __bf16* xq = xb + (size_t)col * IN_F + kw + quad * 8;

    f32x4 acc0 = {0.f, 0.f, 0.f, 0.f};
    f32x4 acc1 = {0.f, 0.f, 0.f, 0.f};

    // preload chunk 0
    float4 w0 = *(const float4*)(wp);
    float4 w1 = *(const float4*)(wp + 4 * IN_F);
    float4 w2 = *(const float4*)(wp + 8 * IN_F);
    float4 w3 = *(const float4*)(wp + 12 * IN_F);
    bf16x8 a00 = *(const bf16x8*)(xq);                     // tokens 0-15, k 0..31
    bf16x8 a01 = *(const bf16x8*)(xq + 32);                // tokens 0-15, k 32..63
    bf16x8 a10 = *(const bf16x8*)(xq + 16 * IN_F);         // tokens 16-31
    bf16x8 a11 = *(const bf16x8*)(xq + 16 * IN_F + 32);

#pragma unroll 2
    for (int c = 0; c < CHUNKS; ++c) {
        uint2 t0 = tern4(w0, thr);
        uint2 t1 = tern4(w1, thr);
        uint2 t2 = tern4(w2, thr);
        uint2 t3 = tern4(w3, thr);
        *(uint2*)(wr)        = t0;
        *(uint2*)(wr + 576)  = t1;
        *(uint2*)(wr + 1152) = t2;
        *(uint2*)(wr + 1728) = t3;

        // prefetch next chunk (w + x) before consuming LDS
        bf16x8 n00 = a00, n01 = a01, n10 = a10, n11 = a11;
        if (c + 1 < CHUNKS) {
            const float*  np = wp + (c + 1) * 64;
            const __bf16* xn = xq + (c + 1) * 64;
            w0  = *(const float4*)(np);
            w1  = *(const float4*)(np + 4 * IN_F);
            w2  = *(const float4*)(np + 8 * IN_F);
            w3  = *(const float4*)(np + 12 * IN_F);
            n00 = *(const bf16x8*)(xn);
            n01 = *(const bf16x8*)(xn + 32);
            n10 = *(const bf16x8*)(xn + 16 * IN_F);
            n11 = *(const bf16x8*)(xn + 16 * IN_F + 32);
        }

        // same-wave DS ordering: reads after writes are coherent
        bf16x8 bw0 = *(const bf16x8*)(rd + quad * 16);         // k 0..31 granule
        bf16x8 bw1 = *(const bf16x8*)(rd + 64 + quad * 16);    // k 32..63 granule
        acc0 = __builtin_amdgcn_mfma_f32_16x16x32_bf16(a00, bw0, acc0, 0, 0, 0);
        acc1 = __builtin_amdgcn_mfma_f32_16x16x32_bf16(a10, bw0, acc1, 0, 0, 0);
        acc0 = __builtin_amdgcn_mfma_f32_16x16x32_bf16(a01, bw1, acc0, 0, 0, 0);
        acc1 = __builtin_amdgcn_mfma_f32_16x16x32_bf16(a11, bw1, acc1, 0, 0, 0);

        a00 = n00; a01 = n01; a10 = n10; a11 = n11;
    }

    __syncthreads();
    float* red  = (float*)smem_raw;
    float* base = red + wv * 512;
#pragma unroll
    for (int r = 0; r < 4; ++r) base[r * 64 + lane]       = acc0[r];
#pragma unroll
    for (int r = 0; r < 4; ++r) base[256 + r * 64 + lane] = acc1[r];
    __syncthreads();

    // 512 outputs (32 tokens x 16 cols), 2 per thread, summed over 4 waves
#pragma unroll
    for (int p = tid; p < 512; p += 256) {
        int t = p >> 4, cc = p & 15;
        int a = t >> 4;
        int q = (t >> 2) & 3;
        int r = t & 3;
        int idx = a * 256 + r * 64 + q * 16 + cc;
        float s = red[idx] + red[512 + idx] + red[1024 + idx] + red[1536 + idx];
        atomicAdd(out + (size_t)t * OUT_F + og * 16 + cc, s * scale);
    }
}

extern "C" void kernel_launch(void* const* d_in, const int* in_sizes, int n_in,
                              void* d_out, int out_size, void* d_ws, size_t ws_size,
                              hipStream_t stream) {
    const float* x = (const float*)d_in[0];   // [32, 4096]
    const float* w = (const float*)d_in[1];   // [11008, 4096]
    float* out     = (float*)d_out;           // [32, 11008]
    double* wsd    = (double*)d_ws;
    uint4* xb      = (uint4*)((char*)d_ws + 64);   // 256 KB bf16 x

    hipMemsetAsync(d_ws, 0, 16, stream);                               // f64 accumulator
    hipMemsetAsync(d_out, 0, sizeof(float) * TOKENS * OUT_F, stream);  // zero for atomics

    absum_xcvt_kernel<<<ABSUM_BLOCKS + XCVT_BLOCKS, 256, 0, stream>>>(w, x, wsd, xb);
    finalize_kernel<<<1, 1, 0, stream>>>(wsd);
    ternary_gemm<<<(OUT_F / 16) * 2, 256, 0, stream>>>(w, (const float*)d_ws,
                                                       (const __bf16*)((char*)d_ws + 64), out);
}

// Round 5
// 279.424 us; speedup vs baseline: 1.2039x; 1.0486x over previous
//
#include <hip/hip_runtime.h>
#include <hip/hip_bf16.h>
#include <stdint.h>

#define IN_F 4096
#define OUT_F 11008
#define TOKENS 32
#define NELEM_W (OUT_F * IN_F)   // 45088768 weights, ~180 MB fp32
#define OUT_ELEMS (TOKENS * OUT_F)   // 352256

typedef __attribute__((ext_vector_type(8))) __bf16 bf16x8;
typedef __attribute__((ext_vector_type(4))) float  f32x4;

// d_ws layout (bytes):
//   [0, 64):           scalars: f[2]=threshold, f[3]=scale
//   [64, 64+256K):     xb  — x converted to bf16
//   [262208, +2.8M):   gemm split-K partials: 2 x 352256 f32
//   [3080256, +8K):    absum per-block partials: 2048 f32
#define XB_OFF    64
#define GPART_OFF 262208
#define APART_OFF 3080256

// fp32 -> bf16 bits (round-to-nearest-even), result in low 16
__device__ __forceinline__ uint32_t bfr(float v) {
    uint32_t u = __float_as_uint(v);
    uint32_t r = u + 0x7FFFu + ((u >> 16) & 1u);
    return r >> 16;
}

// ---------------- pass 1: sum(|w|) partials + x->bf16 conversion ----------------
#define ABSUM_BLOCKS 2048
#define XCVT_BLOCKS  64

__global__ __launch_bounds__(256) void absum_xcvt_kernel(const float* __restrict__ w,
                                                         const float* __restrict__ x,
                                                         float* __restrict__ apart,
                                                         uint4* __restrict__ xb) {
    if (blockIdx.x >= ABSUM_BLOCKS) {
        // x conversion: 16384 threads, 8 floats each
        int i = (blockIdx.x - ABSUM_BLOCKS) * 256 + threadIdx.x;
        const float4* x4 = (const float4*)x;
        float4 a0 = x4[i * 2];
        float4 a1 = x4[i * 2 + 1];
        uint4 o;
        o.x = bfr(a0.x) | (bfr(a0.y) << 16);
        o.y = bfr(a0.z) | (bfr(a0.w) << 16);
        o.z = bfr(a1.x) | (bfr(a1.y) << 16);
        o.w = bfr(a1.z) | (bfr(a1.w) << 16);
        xb[i] = o;
        return;
    }
    int tid = blockIdx.x * blockDim.x + threadIdx.x;
    int stride = ABSUM_BLOCKS * 256;
    const float4* w4 = (const float4*)w;
    const int n4 = NELEM_W / 4;
    float s = 0.f;
    for (int i = tid; i < n4; i += stride) {
        float4 v = w4[i];
        s += fabsf(v.x) + fabsf(v.y) + fabsf(v.z) + fabsf(v.w);
    }
    for (int off = 32; off > 0; off >>= 1)
        s += __shfl_down(s, off, 64);
    __shared__ float wsum[4];
    int lane = threadIdx.x & 63;
    int wv   = threadIdx.x >> 6;
    if (lane == 0) wsum[wv] = s;
    __syncthreads();
    if (threadIdx.x == 0)
        apart[blockIdx.x] = wsum[0] + wsum[1] + wsum[2] + wsum[3];   // plain store
}

// ---------------- pass 1.5: reduce 2048 partials -> thr/scale ----------------
__global__ __launch_bounds__(256) void finalize_kernel(const float* __restrict__ apart,
                                                       float* __restrict__ wsf) {
    float s = 0.f;
#pragma unroll
    for (int j = 0; j < 8; ++j)
        s += apart[threadIdx.x + 256 * j];
    for (int off = 32; off > 0; off >>= 1)
        s += __shfl_down(s, off, 64);
    __shared__ float wsum[4];
    int lane = threadIdx.x & 63;
    int wv   = threadIdx.x >> 6;
    if (lane == 0) wsum[wv] = s;
    __syncthreads();
    if (threadIdx.x == 0) {
        double mean = (double)(wsum[0] + wsum[1] + wsum[2] + wsum[3]) / (double)NELEM_W;
        if (mean < 1e-5) mean = 1e-5;
        float mf = (float)mean;
        wsf[2] = 0.7f * mf;   // threshold
        wsf[3] = mf;          // scale
    }
}

// ---------------- ternarize helpers ----------------
__device__ __forceinline__ uint32_t tern1(float v, float thr) {
    uint32_t u  = __float_as_uint(v);
    uint32_t pm = (u & 0x80000000u) | 0x3F800000u;   // +-1.0f
    return (__builtin_fabsf(v) > thr) ? pm : 0u;
}

// 4 fp32 -> 4 ternary bf16 packed in uint2 (v_perm for the pack)
__device__ __forceinline__ uint2 tern4(float4 b, float thr) {
    uint32_t q0 = tern1(b.x, thr), q1 = tern1(b.y, thr);
    uint32_t q2 = tern1(b.z, thr), q3 = tern1(b.w, thr);
    uint2 r;
    r.x = __builtin_amdgcn_perm(q1, q0, 0x07060302u);   // lo16=q0.hi16, hi16=q1.hi16
    r.y = __builtin_amdgcn_perm(q3, q2, 0x07060302u);
    return r;
}

// ---------------- pass 2: LDS-staged ternary GEMM, atomic-free ----------------
// Grid: 688 o-groups x 2 K-halves = 1376 blocks of 128 (2 waves) — 2752 waves,
// fully resident (~10.7 waves/CU). Wave wv covers 1024 k in 16 chunks of 64.
// Staging instr j: lane l loads 16 B of row og*16 + 4j + (l>>4) at float
// offset (l&15)*4 — 16 fully-used 64B lines per instruction.
// 2-deep register double-buffer of w and x. Partials -> d_ws (plain stores).
#define CHUNKS 16
#define WAVE_LDS 2304          // 16 rows * 144 B
#define SMEM_BYTES 4608        // 2 waves; also covers 2*512*4 reduce buf

__global__ __launch_bounds__(128, 4) void ternary_gemm(const float* __restrict__ w,
                                                       const float* __restrict__ wsf,
                                                       const __bf16* __restrict__ xb,
                                                       float* __restrict__ gpart) {
    __shared__ char smem_raw[SMEM_BYTES];
    const float thr = wsf[2];
    const int og   = blockIdx.x >> 1;
    const int kh   = blockIdx.x & 1;
    const int tid  = threadIdx.x;
    const int wv   = tid >> 6;
    const int lane = tid & 63;
    const int col  = lane & 15;     // fragment: output col in group / token
    const int quad = lane >> 4;     // fragment k sub-block; staging row group
    const int rlan = lane & 15;     // staging: 16-B slot within a row

    const int kw = kh * 2048 + wv * 1024;

    const float* wp = w + (size_t)(og * 16 + quad) * IN_F + kw + rlan * 4;
    char* stage = smem_raw + wv * WAVE_LDS;
    char* wr    = stage + quad * 144 + rlan * 8;   // + j*576 per staging instr
    const char* rd = stage + col * 144;
    const __bf16* xq = xb + (size_t)col * IN_F + kw + quad * 8;

    f32x4 acc0 = {0.f, 0.f, 0.f, 0.f};
    f32x4 acc1 = {0.f, 0.f, 0.f, 0.f};

    float4 wb[2][4];
    bf16x8 xv[2][4];

#pragma unroll
    for (int c = 0; c < 2; ++c) {
        const float*  np = wp + c * 64;
        const __bf16* xn = xq + c * 64;
        wb[c][0] = *(const float4*)(np);
        wb[c][1] = *(const float4*)(np + 4 * IN_F);
        wb[c][2] = *(const float4*)(np + 8 * IN_F);
        wb[c][3] = *(const float4*)(np + 12 * IN_F);
        xv[c][0] = *(const bf16x8*)(xn);
        xv[c][1] = *(const bf16x8*)(xn + 32);
        xv[c][2] = *(const bf16x8*)(xn + 16 * IN_F);
        xv[c][3] = *(const bf16x8*)(xn + 16 * IN_F + 32);
    }

#define GEMM_BODY(c, cur)                                                      \
    {                                                                          \
        uint2 t0 = tern4(wb[cur][0], thr);                                     \
        uint2 t1 = tern4(wb[cur][1], thr);                                     \
        uint2 t2 = tern4(wb[cur][2], thr);                                     \
        uint2 t3 = tern4(wb[cur][3], thr);                                     \
        *(uint2*)(wr)        = t0;                                             \
        *(uint2*)(wr + 576)  = t1;                                             \
        *(uint2*)(wr + 1152) = t2;                                             \
        *(uint2*)(wr + 1728) = t3;                                             \
        bf16x8 a00 = xv[cur][0], a01 = xv[cur][1];                             \
        bf16x8 a10 = xv[cur][2], a11 = xv[cur][3];                             \
        if ((c) + 2 < CHUNKS) {                                                \
            const float*  np = wp + ((c) + 2) * 64;                            \
            const __bf16* xn = xq + ((c) + 2) * 64;                            \
            wb[cur][0] = *(const float4*)(np);                                 \
            wb[cur][1] = *(const float4*)(np + 4 * IN_F);                      \
            wb[cur][2] = *(const float4*)(np + 8 * IN_F);                      \
            wb[cur][3] = *(const float4*)(np + 12 * IN_F);                     \
            xv[cur][0] = *(const bf16x8*)(xn);                                 \
            xv[cur][1] = *(const bf16x8*)(xn + 32);                            \
            xv[cur][2] = *(const bf16x8*)(xn + 16 * IN_F);                     \
            xv[cur][3] = *(const bf16x8*)(xn + 16 * IN_F + 32);                \
        }                                                                      \
        bf16x8 bw0 = *(const bf16x8*)(rd + quad * 16);                         \
        bf16x8 bw1 = *(const bf16x8*)(rd + 64 + quad * 16);                    \
        acc0 = __builtin_amdgcn_mfma_f32_16x16x32_bf16(a00, bw0, acc0, 0, 0, 0); \
        acc1 = __builtin_amdgcn_mfma_f32_16x16x32_bf16(a10, bw0, acc1, 0, 0, 0); \
        acc0 = __builtin_amdgcn_mfma_f32_16x16x32_bf16(a01, bw1, acc0, 0, 0, 0); \
        acc1 = __builtin_amdgcn_mfma_f32_16x16x32_bf16(a11, bw1, acc1, 0, 0, 0); \
    }

    for (int c = 0; c < CHUNKS; c += 2) {
        GEMM_BODY(c, 0)
        GEMM_BODY(c + 1, 1)
    }
#undef GEMM_BODY

    __syncthreads();
    float* red  = (float*)smem_raw;
    float* base = red + wv * 512;
#pragma unroll
    for (int r = 0; r < 4; ++r) base[r * 64 + lane]       = acc0[r];
#pragma unroll
    for (int r = 0; r < 4; ++r) base[256 + r * 64 + lane] = acc1[r];
    __syncthreads();

    // 512 outputs (32 tokens x 16 cols), 4 per thread, summed over 2 waves
    float* gp = gpart + (size_t)kh * OUT_ELEMS;
    for (int p = tid; p < 512; p += 128) {
        int t = p >> 4, cc = p & 15;
        int a = t >> 4;
        int q = (t >> 2) & 3;
        int r = t & 3;
        int idx = a * 256 + r * 64 + q * 16 + cc;
        gp[(size_t)t * OUT_F + og * 16 + cc] = red[idx] + red[512 + idx];
    }
}

// ---------------- pass 3: combine split-K partials ----------------
__global__ __launch_bounds__(256) void combine_kernel(const float* __restrict__ gpart,
                                                      const float* __restrict__ wsf,
                                                      float* __restrict__ out) {
    const float sc = wsf[3];
    int i = blockIdx.x * 256 + threadIdx.x;   // float4 index, 88064 total
    const float4* p0 = (const float4*)gpart;
    const float4* p1 = (const float4*)(gpart + OUT_ELEMS);
    float4 a = p0[i], b = p1[i];
    float4 o;
    o.x = (a.x + b.x) * sc;
    o.y = (a.y + b.y) * sc;
    o.z = (a.z + b.z) * sc;
    o.w = (a.w + b.w) * sc;
    ((float4*)out)[i] = o;
}

extern "C" void kernel_launch(void* const* d_in, const int* in_sizes, int n_in,
                              void* d_out, int out_size, void* d_ws, size_t ws_size,
                              hipStream_t stream) {
    const float* x = (const float*)d_in[0];   // [32, 4096]
    const float* w = (const float*)d_in[1];   // [11008, 4096]
    float* out     = (float*)d_out;           // [32, 11008]
    char* ws       = (char*)d_ws;

    float* wsf     = (float*)ws;
    uint4* xb      = (uint4*)(ws + XB_OFF);
    float* gpart   = (float*)(ws + GPART_OFF);
    float* apart   = (float*)(ws + APART_OFF);

    absum_xcvt_kernel<<<ABSUM_BLOCKS + XCVT_BLOCKS, 256, 0, stream>>>(w, x, apart, xb);
    finalize_kernel<<<1, 256, 0, stream>>>(apart, wsf);
    ternary_gemm<<<(OUT_F / 16) * 2, 128, 0, stream>>>(w, wsf, (const __bf16*)(ws + XB_OFF), gpart);
    combine_kernel<<<OUT_ELEMS / 4 / 256, 256, 0, stream>>>(gpart, wsf, out);
}